// Round 8
// baseline (179.581 us; speedup 1.0000x reference)
//
#include <hip/hip_runtime.h>
#include <hip/hip_bf16.h>
#include <stdint.h>

// ---------------------------------------------------------------------------
// GroundingLoss fused pipeline, R8.
// R2-R7 post-mortem: binding constraint = register budget (unified 512/SIMD
// pool; every reuse scheme blew it -> 1-2 waves/SIMD -> latency exposed) plus
// per-iteration barrier/vmcnt drains. R8: block = 4 waves sharing ONE a-pair
// staged once to LDS (32KB, ONE barrier total); wave = 2a x 2b tiles (64 AGPR
// acc, 4 independent MFMA chains); A per-ks from LDS (2 x ds_read_b128,
// conflict-free); B streamed global->VGPR (compiler-pipelined vmcnt);
// epilogue: 4-way partial accumulators, 4-tile ILP, no stores drained.
// ---------------------------------------------------------------------------

typedef __attribute__((ext_vector_type(8))) short short8;    // 8 bf16 = 16B
typedef __attribute__((ext_vector_type(16))) float float16;  // 32x32 acc

typedef const __attribute__((address_space(1))) unsigned int* gptr_as1;
typedef __attribute__((address_space(3))) unsigned int* lptr_as3;

#define NTOK 256
#define KDIM 256

__device__ __forceinline__ unsigned short f2bf(float f) {
    unsigned int u = __float_as_uint(f);
    unsigned int r = (u + 0x7fffu + ((u >> 16) & 1u)) >> 16;  // RNE
    return (unsigned short)r;
}

__device__ __forceinline__ short8 cvt8(const float* p) {
    float4 f0 = ((const float4*)p)[0];
    float4 f1 = ((const float4*)p)[1];
    short8 v;
    v[0] = (short)f2bf(f0.x); v[1] = (short)f2bf(f0.y);
    v[2] = (short)f2bf(f0.z); v[3] = (short)f2bf(f0.w);
    v[4] = (short)f2bf(f1.x); v[5] = (short)f2bf(f1.y);
    v[6] = (short)f2bf(f1.z); v[7] = (short)f2bf(f1.w);
    return v;
}

// fp32 -> bf16 fragment-major: unit(g, ks, half, l31) = g*1024 + ks*64 + half*32 + l31.
__global__ void conv_kernel(const float* __restrict__ x,
                            const float* __restrict__ z,
                            short8* __restrict__ outbf,
                            float* __restrict__ out0) {
    const int uid = blockIdx.x * 256 + threadIdx.x;
    if (uid == 0) out0[0] = 0.0f;   // loss accumulator (loss_part atomicAdds)
    const int u = uid & 262143;
    const float* src = (uid < 262144) ? x : z;
    const int g  = u >> 10;
    const int r  = u & 1023;
    const int ks = r >> 6;
    const int h  = (r >> 5) & 1;
    const int l  = r & 31;
    outbf[uid] = cvt8(src + ((g * 32 + l) * KDIM + ks * 16 + h * 8));
}

// Softmax-weighted column mean of one 32x32 C-tile -> S[a*NTOK+b].
// 4-way partial accumulators keep VGPR use low so 4 tiles interleave.
__device__ __forceinline__ void tile_epilogue(const float16& c, float* __restrict__ S,
                                              int a, int b, int lane) {
    float m8[8], m4[4];
#pragma unroll
    for (int r = 0; r < 8; r++) m8[r] = fmaxf(c[2 * r], c[2 * r + 1]);
#pragma unroll
    for (int r = 0; r < 4; r++) m4[r] = fmaxf(m8[2 * r], m8[2 * r + 1]);
    float m = fmaxf(fmaxf(m4[0], m4[1]), fmaxf(m4[2], m4[3]));
    m = fmaxf(m, __shfl_xor(m, 32, 64));

    float s0 = 0.f, s1 = 0.f, s2 = 0.f, s3 = 0.f;
    float w0 = 0.f, w1 = 0.f, w2 = 0.f, w3 = 0.f;
#pragma unroll
    for (int r = 0; r < 16; r += 4) {
        float e0 = __expf(c[r + 0] - m);
        float e1 = __expf(c[r + 1] - m);
        float e2 = __expf(c[r + 2] - m);
        float e3 = __expf(c[r + 3] - m);
        s0 += e0; s1 += e1; s2 += e2; s3 += e3;
        w0 = fmaf(e0, c[r + 0], w0);
        w1 = fmaf(e1, c[r + 1], w1);
        w2 = fmaf(e2, c[r + 2], w2);
        w3 = fmaf(e3, c[r + 3], w3);
    }
    float se  = (s0 + s1) + (s2 + s3);
    float swe = (w0 + w1) + (w2 + w3);

    se  += __shfl_xor(se, 32, 64);
    swe += __shfl_xor(swe, 32, 64);
    float cv = swe * __builtin_amdgcn_rcpf(se);
#pragma unroll
    for (int off = 1; off < 32; off <<= 1) cv += __shfl_xor(cv, off, 64);
    if (lane == 0) S[a * NTOK + b] = cv * (1.0f / 32.0f);
}

// grid = 1024 blocks (128 a-pairs x 8 b-chunks), 256 threads.
// Wave w: b-subrange = chunk*32 + w*8 .. +8, in 4 passes of a 2b pair.
template <bool F32SRC>
__global__ __launch_bounds__(256, 3)
void sim_kernel(const short8* __restrict__ xbf, const short8* __restrict__ zbf,
                const float* __restrict__ xf, const float* __restrict__ zf,
                float* __restrict__ S) {
    __shared__ short8 sA[2048];   // 32 KB: one a-pair, full K, fragment-major

    const int tid  = threadIdx.x;
    const int lane = tid & 63;
    const int w    = tid >> 6;
    const int l31  = lane & 31;
    const int half = lane >> 5;

    const int apair = blockIdx.x >> 3;              // 0..127
    const int ag0   = apair * 2, ag1 = ag0 + 1;
    const int bbase = (blockIdx.x & 7) * 32 + w * 8;

    if (!F32SRC) {
        // Stage the a-pair (2048 units = 32 KB) once; the ONLY barrier.
        const short8* asrc = xbf + apair * 2048;
#pragma unroll
        for (int i = 0; i < 8; i++) {
            const short8* g = asrc + i * 256 + w * 64 + lane;
            short8* l = &sA[i * 256 + w * 64];
            __builtin_amdgcn_global_load_lds((gptr_as1)g, (lptr_as3)l, 16, 0, 0);
        }
        __syncthreads();
    }

#pragma unroll 1
    for (int p = 0; p < 4; p++) {
        const int bgA = bbase + 2 * p;
        const int bgB = bgA + 1;

        float16 acc00, acc01, acc10, acc11;
#pragma unroll
        for (int r = 0; r < 16; r++) {
            acc00[r] = 0.f; acc01[r] = 0.f; acc10[r] = 0.f; acc11[r] = 0.f;
        }

        if (F32SRC) {
            const float* fa0 = xf + ((ag0 * 32 + l31) * KDIM + half * 8);
            const float* fa1 = xf + ((ag1 * 32 + l31) * KDIM + half * 8);
            const float* fba = zf + ((bgA * 32 + l31) * KDIM + half * 8);
            const float* fbb = zf + ((bgB * 32 + l31) * KDIM + half * 8);
#pragma unroll
            for (int ks = 0; ks < 16; ks++) {
                short8 A0 = cvt8(fa0 + ks * 16);
                short8 A1 = cvt8(fa1 + ks * 16);
                short8 Ba = cvt8(fba + ks * 16);
                short8 Bb = cvt8(fbb + ks * 16);
                acc00 = __builtin_amdgcn_mfma_f32_32x32x16_bf16(A0, Ba, acc00, 0, 0, 0);
                acc01 = __builtin_amdgcn_mfma_f32_32x32x16_bf16(A0, Bb, acc01, 0, 0, 0);
                acc10 = __builtin_amdgcn_mfma_f32_32x32x16_bf16(A1, Ba, acc10, 0, 0, 0);
                acc11 = __builtin_amdgcn_mfma_f32_32x32x16_bf16(A1, Bb, acc11, 0, 0, 0);
            }
        } else {
            const short8* pba = zbf + bgA * 1024 + lane;
            const short8* pbb = zbf + bgB * 1024 + lane;
#pragma unroll
            for (int ks = 0; ks < 16; ks++) {
                short8 Ba = pba[ks * 64];
                short8 Bb = pbb[ks * 64];
                short8 A0 = sA[ks * 64 + lane];
                short8 A1 = sA[1024 + ks * 64 + lane];
                acc00 = __builtin_amdgcn_mfma_f32_32x32x16_bf16(A0, Ba, acc00, 0, 0, 0);
                acc01 = __builtin_amdgcn_mfma_f32_32x32x16_bf16(A0, Bb, acc01, 0, 0, 0);
                acc10 = __builtin_amdgcn_mfma_f32_32x32x16_bf16(A1, Ba, acc10, 0, 0, 0);
                acc11 = __builtin_amdgcn_mfma_f32_32x32x16_bf16(A1, Bb, acc11, 0, 0, 0);
            }
        }

        tile_epilogue(acc00, S, ag0, bgA, lane);
        tile_epilogue(acc01, S, ag0, bgB, lane);
        tile_epilogue(acc10, S, ag1, bgA, lane);
        tile_epilogue(acc11, S, ag1, bgB, lane);
    }
}

// 64 blocks x 256 threads; wave w handles n = bid*4 + w. One atomicAdd/block.
__global__ void loss_part(const float* __restrict__ S, float* __restrict__ out) {
    const int lane = threadIdx.x & 63;
    const int wid  = threadIdx.x >> 6;
    const int n    = blockIdx.x * 4 + wid;

    float cv[4], rv[4];
#pragma unroll
    for (int k = 0; k < 4; k++) {
        const int t = lane + 64 * k;
        cv[k] = S[t * NTOK + n];
        rv[k] = S[n * NTOK + t];
    }
    float m = fmaxf(fmaxf(cv[0], cv[1]), fmaxf(cv[2], cv[3]));
#pragma unroll
    for (int off = 1; off < 64; off <<= 1) m = fmaxf(m, __shfl_xor(m, off, 64));
    float s = 0.0f;
#pragma unroll
    for (int k = 0; k < 4; k++) s += __expf(cv[k] - m);
#pragma unroll
    for (int off = 1; off < 64; off <<= 1) s += __shfl_xor(s, off, 64);
    float lse_col = m + __logf(s);

    float m2 = fmaxf(fmaxf(rv[0], rv[1]), fmaxf(rv[2], rv[3]));
#pragma unroll
    for (int off = 1; off < 64; off <<= 1) m2 = fmaxf(m2, __shfl_xor(m2, off, 64));
    float s2 = 0.0f;
#pragma unroll
    for (int k = 0; k < 4; k++) s2 += __expf(rv[k] - m2);
#pragma unroll
    for (int off = 1; off < 64; off <<= 1) s2 += __shfl_xor(s2, off, 64);
    float lse_row = m2 + __logf(s2);

    __shared__ float red[4];
    if (lane == 0) {
        float diag = S[n * NTOK + n];
        red[wid] = (lse_col - diag) + (lse_row - diag);
    }
    __syncthreads();
    if (threadIdx.x == 0)
        atomicAdd(out, (red[0] + red[1] + red[2] + red[3]) * (1.0f / 256.0f));
}

__global__ void zero_kernel(float* __restrict__ out) {
    out[0] = 0.0f;
}

extern "C" void kernel_launch(void* const* d_in, const int* in_sizes, int n_in,
                              void* d_out, int out_size, void* d_ws, size_t ws_size,
                              hipStream_t stream) {
    const float* x = (const float*)d_in[0];   // [256,32,256]
    const float* z = (const float*)d_in[1];   // [256,32,256]
    float* out = (float*)d_out;

    const size_t bf_bytes = 524288ull * 16ull;         // 8 MB fragment-major
    const size_t s_bytes  = 256ull * 256ull * 4ull;    // 256 KB

    if (ws_size >= bf_bytes + s_bytes) {
        short8* xbf = (short8*)d_ws;          // 262144 units
        short8* zbf = xbf + 262144;
        float*  S   = (float*)((char*)d_ws + bf_bytes);
        conv_kernel<<<2048, 256, 0, stream>>>(x, z, (short8*)d_ws, out);
        sim_kernel<false><<<1024, 256, 0, stream>>>(xbf, zbf, nullptr, nullptr, S);
        loss_part<<<64, 256, 0, stream>>>(S, out);
    } else {
        float* S = (float*)d_ws;              // 256 KB
        zero_kernel<<<1, 1, 0, stream>>>(out);
        sim_kernel<true><<<1024, 256, 0, stream>>>(nullptr, nullptr, x, z, S);
        loss_part<<<64, 256, 0, stream>>>(S, out);
    }
}

// Round 9
// 120.035 us; speedup vs baseline: 1.4961x; 1.4961x over previous
//
#include <hip/hip_runtime.h>
#include <hip/hip_bf16.h>
#include <hip/hip_fp16.h>
#include <stdint.h>

// ---------------------------------------------------------------------------
// GroundingLoss fused pipeline, R9.
// Invariant solved (R2-R8: 52-60us across 5 memory structures, MfmaUtil ~25%):
// per-tile softmax epilogue had ~8 serial cross-lane shuffles + dependent
// VALU ~ >500 cyc exposed per tile; all waves epilogue in lockstep -> nothing
// hides it (~40us). R9 keeps the R4 skeleton (2a x 2b wave tile, grid 4096,
// 4 waves/SIMD, fragment-major global loads) and cuts the epilogue chain:
// each lane STORES its column value to Sp[a,b,lane] (fp16, 8MB ws) instead of
// the 5-shuffle butterfly; a cheap red_kernel reduces Sp -> S. R8's spill
// lesson: never hold 4 acc tiles through interleaved epilogues.
// ---------------------------------------------------------------------------

typedef __attribute__((ext_vector_type(8))) short short8;    // 8 bf16 = 16B
typedef __attribute__((ext_vector_type(16))) float float16;  // 32x32 acc

#define NTOK 256
#define KDIM 256

__device__ __forceinline__ unsigned short f2bf(float f) {
    unsigned int u = __float_as_uint(f);
    unsigned int r = (u + 0x7fffu + ((u >> 16) & 1u)) >> 16;  // RNE
    return (unsigned short)r;
}

__device__ __forceinline__ short8 cvt8(const float* p) {
    float4 f0 = ((const float4*)p)[0];
    float4 f1 = ((const float4*)p)[1];
    short8 v;
    v[0] = (short)f2bf(f0.x); v[1] = (short)f2bf(f0.y);
    v[2] = (short)f2bf(f0.z); v[3] = (short)f2bf(f0.w);
    v[4] = (short)f2bf(f1.x); v[5] = (short)f2bf(f1.y);
    v[6] = (short)f2bf(f1.z); v[7] = (short)f2bf(f1.w);
    return v;
}

// fp32 -> bf16 fragment-major: unit(g, ks, half, l31) = g*1024 + ks*64 + half*32 + l31.
__global__ void conv_kernel(const float* __restrict__ x,
                            const float* __restrict__ z,
                            short8* __restrict__ outbf,
                            float* __restrict__ out0) {
    const int uid = blockIdx.x * 256 + threadIdx.x;
    if (uid == 0) out0[0] = 0.0f;   // loss accumulator (loss_part atomicAdds)
    const int u = uid & 262143;
    const float* src = (uid < 262144) ? x : z;
    const int g  = u >> 10;
    const int r  = u & 1023;
    const int ks = r >> 6;
    const int h  = (r >> 5) & 1;
    const int l  = r & 31;
    outbf[uid] = cvt8(src + ((g * 32 + l) * KDIM + ks * 16 + h * 8));
}

// Short-chain epilogue: softmax over i for column j=lane&31; per-lane STORE of
// the column value (both halves store the same value; red_kernel divides by 64).
// Serial cross-lane ops: 3 shuffles (was 8).
__device__ __forceinline__ void tile_epilogue_sp(const float16& c, __half* __restrict__ Sp,
                                                 int a, int b, int lane) {
    float m8[8], m4[4];
#pragma unroll
    for (int r = 0; r < 8; r++) m8[r] = fmaxf(c[2 * r], c[2 * r + 1]);
#pragma unroll
    for (int r = 0; r < 4; r++) m4[r] = fmaxf(m8[2 * r], m8[2 * r + 1]);
    float m = fmaxf(fmaxf(m4[0], m4[1]), fmaxf(m4[2], m4[3]));
    m = fmaxf(m, __shfl_xor(m, 32, 64));

    float s0 = 0.f, s1 = 0.f, s2 = 0.f, s3 = 0.f;
    float w0 = 0.f, w1 = 0.f, w2 = 0.f, w3 = 0.f;
#pragma unroll
    for (int r = 0; r < 16; r += 4) {
        float e0 = __expf(c[r + 0] - m);
        float e1 = __expf(c[r + 1] - m);
        float e2 = __expf(c[r + 2] - m);
        float e3 = __expf(c[r + 3] - m);
        s0 += e0; s1 += e1; s2 += e2; s3 += e3;
        w0 = fmaf(e0, c[r + 0], w0);
        w1 = fmaf(e1, c[r + 1], w1);
        w2 = fmaf(e2, c[r + 2], w2);
        w3 = fmaf(e3, c[r + 3], w3);
    }
    float se  = (s0 + s1) + (s2 + s3);
    float swe = (w0 + w1) + (w2 + w3);
    se  += __shfl_xor(se, 32, 64);
    swe += __shfl_xor(swe, 32, 64);
    float cv = swe * __builtin_amdgcn_rcpf(se);
    Sp[(((a << 8) + b) << 6) + lane] = __float2half_rn(cv);
}

// Butterfly epilogue (fallback when ws can't hold Sp) — the R4-proven path.
__device__ __forceinline__ void tile_epilogue_bf(const float16& c, float* __restrict__ S,
                                                 int a, int b, int lane) {
    float m8[8], m4[4];
#pragma unroll
    for (int r = 0; r < 8; r++) m8[r] = fmaxf(c[2 * r], c[2 * r + 1]);
#pragma unroll
    for (int r = 0; r < 4; r++) m4[r] = fmaxf(m8[2 * r], m8[2 * r + 1]);
    float m = fmaxf(fmaxf(m4[0], m4[1]), fmaxf(m4[2], m4[3]));
    m = fmaxf(m, __shfl_xor(m, 32, 64));

    float s0 = 0.f, s1 = 0.f, s2 = 0.f, s3 = 0.f;
    float w0 = 0.f, w1 = 0.f, w2 = 0.f, w3 = 0.f;
#pragma unroll
    for (int r = 0; r < 16; r += 4) {
        float e0 = __expf(c[r + 0] - m);
        float e1 = __expf(c[r + 1] - m);
        float e2 = __expf(c[r + 2] - m);
        float e3 = __expf(c[r + 3] - m);
        s0 += e0; s1 += e1; s2 += e2; s3 += e3;
        w0 = fmaf(e0, c[r + 0], w0);
        w1 = fmaf(e1, c[r + 1], w1);
        w2 = fmaf(e2, c[r + 2], w2);
        w3 = fmaf(e3, c[r + 3], w3);
    }
    float se  = (s0 + s1) + (s2 + s3);
    float swe = (w0 + w1) + (w2 + w3);
    se  += __shfl_xor(se, 32, 64);
    swe += __shfl_xor(swe, 32, 64);
    float cv = swe * __builtin_amdgcn_rcpf(se);
#pragma unroll
    for (int off = 1; off < 32; off <<= 1) cv += __shfl_xor(cv, off, 64);
    if (lane == 0) S[a * NTOK + b] = cv * (1.0f / 32.0f);
}

// grid = 4096 (64 a-groups x 64 b-groups of 4), 256 threads, 4 waves/SIMD.
template <bool F32SRC, bool SPSTORE>
__global__ __launch_bounds__(256, 4)
void sim_kernel(const short8* __restrict__ xbf, const short8* __restrict__ zbf,
                const float* __restrict__ xf, const float* __restrict__ zf,
                __half* __restrict__ Sp, float* __restrict__ S) {
    const int tid  = threadIdx.x;
    const int lane = tid & 63;
    const int wid  = tid >> 6;
    const int aw   = wid >> 1;
    const int bw   = wid & 1;
    const int l31  = lane & 31;
    const int half = lane >> 5;
    const int bid  = blockIdx.x;
    const int a0   = (bid >> 6) * 4;
    const int b0   = (bid & 63) * 4;

    const int ag = a0 + 2 * aw;
    const int bg = b0 + 2 * bw;

    const short8* pa = xbf + ag * 1024 + lane;
    const short8* pb = zbf + bg * 1024 + lane;

    const float* fa = xf + ((ag * 32 + l31) * KDIM + half * 8);
    const float* fb = zf + ((bg * 32 + l31) * KDIM + half * 8);

    float16 acc[2][2];
#pragma unroll
    for (int ai = 0; ai < 2; ai++)
#pragma unroll
        for (int bi = 0; bi < 2; bi++)
#pragma unroll
            for (int r = 0; r < 16; r++) acc[ai][bi][r] = 0.0f;

#pragma unroll 4
    for (int ks = 0; ks < 16; ks++) {
        short8 a0f, a1f, b0f, b1f;
        if (F32SRC) {
            a0f = cvt8(fa + ks * 16);
            a1f = cvt8(fa + 32 * KDIM + ks * 16);
            b0f = cvt8(fb + ks * 16);
            b1f = cvt8(fb + 32 * KDIM + ks * 16);
        } else {
            const int off = ks * 64;
            a0f = pa[off];
            a1f = pa[off + 1024];
            b0f = pb[off];
            b1f = pb[off + 1024];
        }
        acc[0][0] = __builtin_amdgcn_mfma_f32_32x32x16_bf16(a0f, b0f, acc[0][0], 0, 0, 0);
        acc[0][1] = __builtin_amdgcn_mfma_f32_32x32x16_bf16(a0f, b1f, acc[0][1], 0, 0, 0);
        acc[1][0] = __builtin_amdgcn_mfma_f32_32x32x16_bf16(a1f, b0f, acc[1][0], 0, 0, 0);
        acc[1][1] = __builtin_amdgcn_mfma_f32_32x32x16_bf16(a1f, b1f, acc[1][1], 0, 0, 0);
    }

#pragma unroll
    for (int ai = 0; ai < 2; ai++)
#pragma unroll
        for (int bi = 0; bi < 2; bi++) {
            if (SPSTORE) tile_epilogue_sp(acc[ai][bi], Sp, ag + ai, bg + bi, lane);
            else         tile_epilogue_bf(acc[ai][bi], S,  ag + ai, bg + bi, lane);
        }
}

// Sp [65536 tiles][64 fp16] -> S [256x256] fp32 (mean/64; halves duplicated).
__global__ void red_kernel(const __half* __restrict__ Sp, float* __restrict__ S) {
    const int t = blockIdx.x * 256 + threadIdx.x;   // tile id = a*256+b
    const __half2* h2 = (const __half2*)(Sp + (size_t)t * 64);
    float s = 0.0f;
#pragma unroll
    for (int i = 0; i < 32; i++) {
        float2 f = __half22float2(h2[i]);
        s += f.x + f.y;
    }
    S[t] = s * (1.0f / 64.0f);
}

// 64 blocks x 256 threads; wave w handles n = bid*4 + w. One atomicAdd/block.
__global__ void loss_part(const float* __restrict__ S, float* __restrict__ out) {
    const int lane = threadIdx.x & 63;
    const int wid  = threadIdx.x >> 6;
    const int n    = blockIdx.x * 4 + wid;

    float cv[4], rv[4];
#pragma unroll
    for (int k = 0; k < 4; k++) {
        const int t = lane + 64 * k;
        cv[k] = S[t * NTOK + n];
        rv[k] = S[n * NTOK + t];
    }
    float m = fmaxf(fmaxf(cv[0], cv[1]), fmaxf(cv[2], cv[3]));
#pragma unroll
    for (int off = 1; off < 64; off <<= 1) m = fmaxf(m, __shfl_xor(m, off, 64));
    float s = 0.0f;
#pragma unroll
    for (int k = 0; k < 4; k++) s += __expf(cv[k] - m);
#pragma unroll
    for (int off = 1; off < 64; off <<= 1) s += __shfl_xor(s, off, 64);
    float lse_col = m + __logf(s);

    float m2 = fmaxf(fmaxf(rv[0], rv[1]), fmaxf(rv[2], rv[3]));
#pragma unroll
    for (int off = 1; off < 64; off <<= 1) m2 = fmaxf(m2, __shfl_xor(m2, off, 64));
    float s2 = 0.0f;
#pragma unroll
    for (int k = 0; k < 4; k++) s2 += __expf(rv[k] - m2);
#pragma unroll
    for (int off = 1; off < 64; off <<= 1) s2 += __shfl_xor(s2, off, 64);
    float lse_row = m2 + __logf(s2);

    __shared__ float red[4];
    if (lane == 0) {
        float diag = S[n * NTOK + n];
        red[wid] = (lse_col - diag) + (lse_row - diag);
    }
    __syncthreads();
    if (threadIdx.x == 0)
        atomicAdd(out, (red[0] + red[1] + red[2] + red[3]) * (1.0f / 256.0f));
}

__global__ void zero_kernel(float* __restrict__ out) {
    out[0] = 0.0f;
}

extern "C" void kernel_launch(void* const* d_in, const int* in_sizes, int n_in,
                              void* d_out, int out_size, void* d_ws, size_t ws_size,
                              hipStream_t stream) {
    const float* x = (const float*)d_in[0];   // [256,32,256]
    const float* z = (const float*)d_in[1];   // [256,32,256]
    float* out = (float*)d_out;

    const size_t bf_bytes = 524288ull * 16ull;           // 8 MB fragment-major
    const size_t sp_bytes = 65536ull * 64ull * 2ull;     // 8 MB fp16 Sp
    const size_t s_bytes  = 256ull * 256ull * 4ull;      // 256 KB

    if (ws_size >= bf_bytes + sp_bytes + s_bytes) {
        short8* xbf = (short8*)d_ws;
        short8* zbf = xbf + 262144;
        __half* Sp  = (__half*)((char*)d_ws + bf_bytes);
        float*  S   = (float*)((char*)d_ws + bf_bytes + sp_bytes);
        conv_kernel<<<2048, 256, 0, stream>>>(x, z, (short8*)d_ws, out);
        sim_kernel<false, true><<<4096, 256, 0, stream>>>(xbf, zbf, nullptr, nullptr, Sp, S);
        red_kernel<<<256, 256, 0, stream>>>(Sp, S);
        loss_part<<<64, 256, 0, stream>>>(S, out);
    } else if (ws_size >= bf_bytes + s_bytes) {
        short8* xbf = (short8*)d_ws;
        short8* zbf = xbf + 262144;
        float*  S   = (float*)((char*)d_ws + bf_bytes);
        conv_kernel<<<2048, 256, 0, stream>>>(x, z, (short8*)d_ws, out);
        sim_kernel<false, false><<<4096, 256, 0, stream>>>(xbf, zbf, nullptr, nullptr, nullptr, S);
        loss_part<<<64, 256, 0, stream>>>(S, out);
    } else {
        float* S = (float*)d_ws;              // 256 KB
        zero_kernel<<<1, 1, 0, stream>>>(out);
        sim_kernel<true, false><<<4096, 256, 0, stream>>>(nullptr, nullptr, x, z, nullptr, S);
        loss_part<<<64, 256, 0, stream>>>(S, out);
    }
}

// Round 10
// 109.731 us; speedup vs baseline: 1.6366x; 1.0939x over previous
//
#include <hip/hip_runtime.h>
#include <hip/hip_bf16.h>
#include <hip/hip_fp16.h>
#include <stdint.h>

// ---------------------------------------------------------------------------
// GroundingLoss fused pipeline, R10.
// R2-R9: single-pipe operand feeds cap at ~20us (L1 port 64 B/cyc needs 512B
// per 8-cyc MFMA slot; ds_read_b128 ~85 B/cyc) and ran at ~50% of that.
// R10 splits: A (4 groups, full K) staged ONCE into 64KB LDS (one barrier,
// immediate-offset ds_read_b128); B streamed fragment-major from global with
// register prefetch. Wave tile 4a x 2b (128 AGPR acc, 8 chains), block =
// 4 waves = 4a x 8b, grid 2048 (same-b blocks share an XCD -> B L2-local).
// Per-CU: MFMA 13.65us (binding), L1 10.2us, LDS ~11us, VALU ~8us.
// ---------------------------------------------------------------------------

typedef __attribute__((ext_vector_type(8))) short short8;    // 8 bf16 = 16B
typedef __attribute__((ext_vector_type(16))) float float16;  // 32x32 acc

typedef const __attribute__((address_space(1))) unsigned int* gptr_as1;
typedef __attribute__((address_space(3))) unsigned int* lptr_as3;

#define NTOK 256
#define KDIM 256

__device__ __forceinline__ unsigned short f2bf(float f) {
    unsigned int u = __float_as_uint(f);
    unsigned int r = (u + 0x7fffu + ((u >> 16) & 1u)) >> 16;  // RNE
    return (unsigned short)r;
}

__device__ __forceinline__ short8 cvt8(const float* p) {
    float4 f0 = ((const float4*)p)[0];
    float4 f1 = ((const float4*)p)[1];
    short8 v;
    v[0] = (short)f2bf(f0.x); v[1] = (short)f2bf(f0.y);
    v[2] = (short)f2bf(f0.z); v[3] = (short)f2bf(f0.w);
    v[4] = (short)f2bf(f1.x); v[5] = (short)f2bf(f1.y);
    v[6] = (short)f2bf(f1.z); v[7] = (short)f2bf(f1.w);
    return v;
}

// fp32 -> bf16 fragment-major: unit(g, ks, half, l31) = g*1024 + ks*64 + half*32 + l31.
__global__ void conv_kernel(const float* __restrict__ x,
                            const float* __restrict__ z,
                            short8* __restrict__ outbf,
                            float* __restrict__ out0) {
    const int uid = blockIdx.x * 256 + threadIdx.x;
    if (uid == 0) out0[0] = 0.0f;   // loss accumulator (loss_part atomicAdds)
    const int u = uid & 262143;
    const float* src = (uid < 262144) ? x : z;
    const int g  = u >> 10;
    const int r  = u & 1023;
    const int ks = r >> 6;
    const int h  = (r >> 5) & 1;
    const int l  = r & 31;
    outbf[uid] = cvt8(src + ((g * 32 + l) * KDIM + ks * 16 + h * 8));
}

// Short-chain epilogue: softmax over i for column j=lane&31; per-lane store of
// the column value to Sp[a,b,lane] (halves duplicated; red_kernel divides by 64).
__device__ __forceinline__ void tile_epilogue_sp(const float16& c, __half* __restrict__ Sp,
                                                 int a, int b, int lane) {
    float m8[8], m4[4];
#pragma unroll
    for (int r = 0; r < 8; r++) m8[r] = fmaxf(c[2 * r], c[2 * r + 1]);
#pragma unroll
    for (int r = 0; r < 4; r++) m4[r] = fmaxf(m8[2 * r], m8[2 * r + 1]);
    float m = fmaxf(fmaxf(m4[0], m4[1]), fmaxf(m4[2], m4[3]));
    m = fmaxf(m, __shfl_xor(m, 32, 64));

    float s0 = 0.f, s1 = 0.f, s2 = 0.f, s3 = 0.f;
    float w0 = 0.f, w1 = 0.f, w2 = 0.f, w3 = 0.f;
#pragma unroll
    for (int r = 0; r < 16; r += 4) {
        float e0 = __expf(c[r + 0] - m);
        float e1 = __expf(c[r + 1] - m);
        float e2 = __expf(c[r + 2] - m);
        float e3 = __expf(c[r + 3] - m);
        s0 += e0; s1 += e1; s2 += e2; s3 += e3;
        w0 = fmaf(e0, c[r + 0], w0);
        w1 = fmaf(e1, c[r + 1], w1);
        w2 = fmaf(e2, c[r + 2], w2);
        w3 = fmaf(e3, c[r + 3], w3);
    }
    float se  = (s0 + s1) + (s2 + s3);
    float swe = (w0 + w1) + (w2 + w3);
    se  += __shfl_xor(se, 32, 64);
    swe += __shfl_xor(swe, 32, 64);
    float cv = swe * __builtin_amdgcn_rcpf(se);
    Sp[(((a << 8) + b) << 6) + lane] = __float2half_rn(cv);
}

// Butterfly epilogue (fallback when ws can't hold Sp).
__device__ __forceinline__ void tile_epilogue_bf(const float16& c, float* __restrict__ S,
                                                 int a, int b, int lane) {
    float m8[8], m4[4];
#pragma unroll
    for (int r = 0; r < 8; r++) m8[r] = fmaxf(c[2 * r], c[2 * r + 1]);
#pragma unroll
    for (int r = 0; r < 4; r++) m4[r] = fmaxf(m8[2 * r], m8[2 * r + 1]);
    float m = fmaxf(fmaxf(m4[0], m4[1]), fmaxf(m4[2], m4[3]));
    m = fmaxf(m, __shfl_xor(m, 32, 64));

    float s0 = 0.f, s1 = 0.f, s2 = 0.f, s3 = 0.f;
    float w0 = 0.f, w1 = 0.f, w2 = 0.f, w3 = 0.f;
#pragma unroll
    for (int r = 0; r < 16; r += 4) {
        float e0 = __expf(c[r + 0] - m);
        float e1 = __expf(c[r + 1] - m);
        float e2 = __expf(c[r + 2] - m);
        float e3 = __expf(c[r + 3] - m);
        s0 += e0; s1 += e1; s2 += e2; s3 += e3;
        w0 = fmaf(e0, c[r + 0], w0);
        w1 = fmaf(e1, c[r + 1], w1);
        w2 = fmaf(e2, c[r + 2], w2);
        w3 = fmaf(e3, c[r + 3], w3);
    }
    float se  = (s0 + s1) + (s2 + s3);
    float swe = (w0 + w1) + (w2 + w3);
    se  += __shfl_xor(se, 32, 64);
    swe += __shfl_xor(swe, 32, 64);
    float cv = swe * __builtin_amdgcn_rcpf(se);
#pragma unroll
    for (int off = 1; off < 32; off <<= 1) cv += __shfl_xor(cv, off, 64);
    if (lane == 0) S[a * NTOK + b] = cv * (1.0f / 32.0f);
}

#define MFMA_BF16 __builtin_amdgcn_mfma_f32_32x32x16_bf16

// grid = 2048 (64 a-blocks x 32 b-blocks), 256 threads, 2 waves/SIMD.
// Block covers a-groups ablk*4..+3 (LDS) and b-groups bblk*8..+7 (2 per wave).
template <bool F32SRC, bool SPSTORE>
__global__ __launch_bounds__(256, 2)
void sim_kernel(const short8* __restrict__ xbf, const short8* __restrict__ zbf,
                const float* __restrict__ xf, const float* __restrict__ zf,
                __half* __restrict__ Sp, float* __restrict__ S) {
    __shared__ short8 sA[4096];   // 64 KB: 4 a-groups, full K, fragment-major

    const int tid  = threadIdx.x;
    const int lane = tid & 63;
    const int w    = tid >> 6;
    const int l31  = lane & 31;
    const int half = lane >> 5;

    const int ablk = blockIdx.x >> 5;        // 0..63
    const int bblk = blockIdx.x & 31;        // 0..31
    const int ag0  = ablk * 4;
    const int bg0  = bblk * 8 + w * 2;       // wave's 2 b-groups

    float16 acc[4][2];
#pragma unroll
    for (int ai = 0; ai < 4; ai++)
#pragma unroll
        for (int bi = 0; bi < 2; bi++)
#pragma unroll
            for (int r = 0; r < 16; r++) acc[ai][bi][r] = 0.0f;

    if (!F32SRC) {
        // ---- stage A once: 4096 units = 64 KB; the ONLY barrier ----
        const short8* asrc = xbf + (size_t)ablk * 4096;
#pragma unroll
        for (int i = 0; i < 16; i++) {
            const short8* g = asrc + i * 256 + w * 64 + lane;
            short8* l = &sA[i * 256 + w * 64];
            __builtin_amdgcn_global_load_lds((gptr_as1)g, (lptr_as3)l, 16, 0, 0);
        }
        __syncthreads();

        const short8* pb0 = zbf + (bg0 + 0) * 1024 + lane;
        const short8* pb1 = zbf + (bg0 + 1) * 1024 + lane;

        short8 Ba = pb0[0];
        short8 Bb = pb1[0];
#pragma unroll
        for (int ks = 0; ks < 16; ks++) {
            short8 Na, Nb;
            if (ks < 15) { Na = pb0[(ks + 1) * 64]; Nb = pb1[(ks + 1) * 64]; }
            short8 A0 = sA[ks * 64 + lane];
            short8 A1 = sA[1024 + ks * 64 + lane];
            short8 A2 = sA[2048 + ks * 64 + lane];
            short8 A3 = sA[3072 + ks * 64 + lane];
            acc[0][0] = MFMA_BF16(A0, Ba, acc[0][0], 0, 0, 0);
            acc[0][1] = MFMA_BF16(A0, Bb, acc[0][1], 0, 0, 0);
            acc[1][0] = MFMA_BF16(A1, Ba, acc[1][0], 0, 0, 0);
            acc[1][1] = MFMA_BF16(A1, Bb, acc[1][1], 0, 0, 0);
            acc[2][0] = MFMA_BF16(A2, Ba, acc[2][0], 0, 0, 0);
            acc[2][1] = MFMA_BF16(A2, Bb, acc[2][1], 0, 0, 0);
            acc[3][0] = MFMA_BF16(A3, Ba, acc[3][0], 0, 0, 0);
            acc[3][1] = MFMA_BF16(A3, Bb, acc[3][1], 0, 0, 0);
            Ba = Na; Bb = Nb;
        }
    } else {
        // Correctness fallback: direct fp32 reads + in-flight convert.
        const float* fb0 = zf + (((bg0 + 0) * 32 + l31) * KDIM + half * 8);
        const float* fb1 = zf + (((bg0 + 1) * 32 + l31) * KDIM + half * 8);
#pragma unroll 1
        for (int ks = 0; ks < 16; ks++) {
            short8 Ba = cvt8(fb0 + ks * 16);
            short8 Bb = cvt8(fb1 + ks * 16);
#pragma unroll
            for (int ai = 0; ai < 4; ai++) {
                const float* fa = xf + (((ag0 + ai) * 32 + l31) * KDIM + half * 8);
                short8 Af = cvt8(fa + ks * 16);
                acc[ai][0] = MFMA_BF16(Af, Ba, acc[ai][0], 0, 0, 0);
                acc[ai][1] = MFMA_BF16(Af, Bb, acc[ai][1], 0, 0, 0);
            }
        }
    }

#pragma unroll
    for (int ai = 0; ai < 4; ai++)
#pragma unroll
        for (int bi = 0; bi < 2; bi++) {
            if (SPSTORE) tile_epilogue_sp(acc[ai][bi], Sp, ag0 + ai, bg0 + bi, lane);
            else         tile_epilogue_bf(acc[ai][bi], S,  ag0 + ai, bg0 + bi, lane);
        }
}

// Sp [65536 tiles][64 fp16] -> S [256x256] fp32 (mean/64; halves duplicated).
__global__ void red_kernel(const __half* __restrict__ Sp, float* __restrict__ S) {
    const int t = blockIdx.x * 256 + threadIdx.x;   // tile id = a*256+b
    const __half2* h2 = (const __half2*)(Sp + (size_t)t * 64);
    float s = 0.0f;
#pragma unroll
    for (int i = 0; i < 32; i++) {
        float2 f = __half22float2(h2[i]);
        s += f.x + f.y;
    }
    S[t] = s * (1.0f / 64.0f);
}

// 64 blocks x 256 threads; wave w handles n = bid*4 + w. One atomicAdd/block.
__global__ void loss_part(const float* __restrict__ S, float* __restrict__ out) {
    const int lane = threadIdx.x & 63;
    const int wid  = threadIdx.x >> 6;
    const int n    = blockIdx.x * 4 + wid;

    float cv[4], rv[4];
#pragma unroll
    for (int k = 0; k < 4; k++) {
        const int t = lane + 64 * k;
        cv[k] = S[t * NTOK + n];
        rv[k] = S[n * NTOK + t];
    }
    float m = fmaxf(fmaxf(cv[0], cv[1]), fmaxf(cv[2], cv[3]));
#pragma unroll
    for (int off = 1; off < 64; off <<= 1) m = fmaxf(m, __shfl_xor(m, off, 64));
    float s = 0.0f;
#pragma unroll
    for (int k = 0; k < 4; k++) s += __expf(cv[k] - m);
#pragma unroll
    for (int off = 1; off < 64; off <<= 1) s += __shfl_xor(s, off, 64);
    float lse_col = m + __logf(s);

    float m2 = fmaxf(fmaxf(rv[0], rv[1]), fmaxf(rv[2], rv[3]));
#pragma unroll
    for (int off = 1; off < 64; off <<= 1) m2 = fmaxf(m2, __shfl_xor(m2, off, 64));
    float s2 = 0.0f;
#pragma unroll
    for (int k = 0; k < 4; k++) s2 += __expf(rv[k] - m2);
#pragma unroll
    for (int off = 1; off < 64; off <<= 1) s2 += __shfl_xor(s2, off, 64);
    float lse_row = m2 + __logf(s2);

    __shared__ float red[4];
    if (lane == 0) {
        float diag = S[n * NTOK + n];
        red[wid] = (lse_col - diag) + (lse_row - diag);
    }
    __syncthreads();
    if (threadIdx.x == 0)
        atomicAdd(out, (red[0] + red[1] + red[2] + red[3]) * (1.0f / 256.0f));
}

__global__ void zero_kernel(float* __restrict__ out) {
    out[0] = 0.0f;
}

extern "C" void kernel_launch(void* const* d_in, const int* in_sizes, int n_in,
                              void* d_out, int out_size, void* d_ws, size_t ws_size,
                              hipStream_t stream) {
    const float* x = (const float*)d_in[0];   // [256,32,256]
    const float* z = (const float*)d_in[1];   // [256,32,256]
    float* out = (float*)d_out;

    const size_t bf_bytes = 524288ull * 16ull;           // 8 MB fragment-major
    const size_t sp_bytes = 65536ull * 64ull * 2ull;     // 8 MB fp16 Sp
    const size_t s_bytes  = 256ull * 256ull * 4ull;      // 256 KB

    if (ws_size >= bf_bytes + sp_bytes + s_bytes) {
        short8* xbf = (short8*)d_ws;
        short8* zbf = xbf + 262144;
        __half* Sp  = (__half*)((char*)d_ws + bf_bytes);
        float*  S   = (float*)((char*)d_ws + bf_bytes + sp_bytes);
        conv_kernel<<<2048, 256, 0, stream>>>(x, z, (short8*)d_ws, out);
        sim_kernel<false, true><<<2048, 256, 0, stream>>>(xbf, zbf, nullptr, nullptr, Sp, S);
        red_kernel<<<256, 256, 0, stream>>>(Sp, S);
        loss_part<<<64, 256, 0, stream>>>(S, out);
    } else if (ws_size >= bf_bytes + s_bytes) {
        short8* xbf = (short8*)d_ws;
        short8* zbf = xbf + 262144;
        float*  S   = (float*)((char*)d_ws + bf_bytes);
        conv_kernel<<<2048, 256, 0, stream>>>(x, z, (short8*)d_ws, out);
        sim_kernel<false, false><<<2048, 256, 0, stream>>>(xbf, zbf, nullptr, nullptr, nullptr, S);
        loss_part<<<64, 256, 0, stream>>>(S, out);
    } else {
        float* S = (float*)d_ws;              // 256 KB
        zero_kernel<<<1, 1, 0, stream>>>(out);
        sim_kernel<true, false><<<2048, 256, 0, stream>>>(nullptr, nullptr, x, z, nullptr, S);
        loss_part<<<64, 256, 0, stream>>>(S, out);
    }
}

// Round 11
// 97.157 us; speedup vs baseline: 1.8484x; 1.1294x over previous
//
#include <hip/hip_runtime.h>
#include <hip/hip_bf16.h>
#include <hip/hip_fp16.h>
#include <stdint.h>

// ---------------------------------------------------------------------------
// GroundingLoss fused pipeline, R11.
// R10 found the fixed ~50us: harness poisons the 256MB ws (44.7us fill) inside
// the timed window every replay -> floor ~50us + kernels. sim was still ~41us
// vs 13.8us bf16 MFMA floor with balanced-but-unoverlapped pipe demands.
// R11: MX-fp8 path. mfma_scale_f32_32x32x64_f8f6f4 (A=B=E4M3, constant scale
// 2^0 = byte 127 in all scale positions -> scale-select semantics moot):
// 2x MFMA rate (floor 7.3us/CU), operand bytes halved (LDS 6.4us, L1 5us).
// A/B use the SAME fragment mapping (row/col=lane&31, k-half=lane>>5, lo/hi
// 16B planes) so any within-lane k permutation cancels. C/D layout is
// shape-determined (same as bf16 32x32) -> epilogue unchanged.
// Skeleton = R10: A (4 groups) staged once to 32KB LDS, one barrier; B
// streamed fragment-major from global; wave tile 4a x 2b; Sp store epilogue.
// ---------------------------------------------------------------------------

typedef __attribute__((ext_vector_type(8))) short short8;    // 8 bf16 = 16B
typedef __attribute__((ext_vector_type(16))) float float16;  // 32x32 acc
typedef __attribute__((ext_vector_type(8))) int int8v;       // fp8 K=64 frag
typedef __attribute__((ext_vector_type(4))) int int4v;       // 16B

typedef const __attribute__((address_space(1))) unsigned int* gptr_as1;
typedef __attribute__((address_space(3))) unsigned int* lptr_as3;

#define NTOK 256
#define KDIM 256

__device__ __forceinline__ unsigned short f2bf(float f) {
    unsigned int u = __float_as_uint(f);
    unsigned int r = (u + 0x7fffu + ((u >> 16) & 1u)) >> 16;  // RNE
    return (unsigned short)r;
}

__device__ __forceinline__ short8 cvt8(const float* p) {
    float4 f0 = ((const float4*)p)[0];
    float4 f1 = ((const float4*)p)[1];
    short8 v;
    v[0] = (short)f2bf(f0.x); v[1] = (short)f2bf(f0.y);
    v[2] = (short)f2bf(f0.z); v[3] = (short)f2bf(f0.w);
    v[4] = (short)f2bf(f1.x); v[5] = (short)f2bf(f1.y);
    v[6] = (short)f2bf(f1.z); v[7] = (short)f2bf(f1.w);
    return v;
}

// ======================= fp8 path =======================
// q layout (int4v units of 16B): [0..65535] x-lo, [65536..] x-hi,
// [131072..] z-lo, [196608..] z-hi. Unit idx = (g*4 + ks)*64 + lane;
// lane: row = lane&31, k0 = ks*64 + (lane>>5)*32; lo = k0..+15, hi = k0+16..31.
__global__ void conv_fp8(const float* __restrict__ x,
                         const float* __restrict__ z,
                         int4v* __restrict__ q,
                         float* __restrict__ out0) {
    const int uid = blockIdx.x * 256 + threadIdx.x;   // < 131072
    if (uid == 0) out0[0] = 0.0f;                     // loss accumulator
    const int tensor = uid >> 16;                     // 0 = x, 1 = z
    const int idx    = uid & 65535;
    const int g    = idx >> 8;
    const int r    = idx & 255;
    const int ks   = r >> 6;
    const int lane = r & 63;
    const int row  = g * 32 + (lane & 31);
    const int k0   = ks * 64 + (lane >> 5) * 32;
    const float4* p = (const float4*)((tensor ? z : x) + row * KDIM + k0);

    int4v lo, hi;
#pragma unroll
    for (int i = 0; i < 4; i++) {
        float4 f = p[i];
        int v = __builtin_amdgcn_cvt_pk_fp8_f32(f.x, f.y, 0, false);
        v = __builtin_amdgcn_cvt_pk_fp8_f32(f.z, f.w, v, true);
        lo[i] = v;
    }
#pragma unroll
    for (int i = 0; i < 4; i++) {
        float4 f = p[4 + i];
        int v = __builtin_amdgcn_cvt_pk_fp8_f32(f.x, f.y, 0, false);
        v = __builtin_amdgcn_cvt_pk_fp8_f32(f.z, f.w, v, true);
        hi[i] = v;
    }
    q[tensor * 131072 + idx]         = lo;
    q[tensor * 131072 + 65536 + idx] = hi;
}

__device__ __forceinline__ int8v mk8(int4v lo, int4v hi) {
    int8v r;
    r[0] = lo[0]; r[1] = lo[1]; r[2] = lo[2]; r[3] = lo[3];
    r[4] = hi[0]; r[5] = hi[1]; r[6] = hi[2]; r[7] = hi[3];
    return r;
}

#define MFMA_FP8(a, b, c) \
    __builtin_amdgcn_mfma_scale_f32_32x32x64_f8f6f4((a), (b), (c), 0, 0, 0, 0x7F7F7F7F, 0, 0x7F7F7F7F)

// Short-chain epilogue: softmax over i for column j=lane&31; per-lane store
// to Sp[a,b,lane] (halves duplicated; red_kernel divides by 64).
__device__ __forceinline__ void tile_epilogue_sp(const float16& c, __half* __restrict__ Sp,
                                                 int a, int b, int lane) {
    float m8[8], m4[4];
#pragma unroll
    for (int r = 0; r < 8; r++) m8[r] = fmaxf(c[2 * r], c[2 * r + 1]);
#pragma unroll
    for (int r = 0; r < 4; r++) m4[r] = fmaxf(m8[2 * r], m8[2 * r + 1]);
    float m = fmaxf(fmaxf(m4[0], m4[1]), fmaxf(m4[2], m4[3]));
    m = fmaxf(m, __shfl_xor(m, 32, 64));

    float s0 = 0.f, s1 = 0.f, s2 = 0.f, s3 = 0.f;
    float w0 = 0.f, w1 = 0.f, w2 = 0.f, w3 = 0.f;
#pragma unroll
    for (int r = 0; r < 16; r += 4) {
        float e0 = __expf(c[r + 0] - m);
        float e1 = __expf(c[r + 1] - m);
        float e2 = __expf(c[r + 2] - m);
        float e3 = __expf(c[r + 3] - m);
        s0 += e0; s1 += e1; s2 += e2; s3 += e3;
        w0 = fmaf(e0, c[r + 0], w0);
        w1 = fmaf(e1, c[r + 1], w1);
        w2 = fmaf(e2, c[r + 2], w2);
        w3 = fmaf(e3, c[r + 3], w3);
    }
    float se  = (s0 + s1) + (s2 + s3);
    float swe = (w0 + w1) + (w2 + w3);
    se  += __shfl_xor(se, 32, 64);
    swe += __shfl_xor(swe, 32, 64);
    float cv = swe * __builtin_amdgcn_rcpf(se);
    Sp[(((a << 8) + b) << 6) + lane] = __float2half_rn(cv);
}

// grid = 2048 (64 a-blocks x 32 b-blocks), 256 threads, 2 waves/SIMD.
__global__ __launch_bounds__(256, 2)
void sim_fp8(const int4v* __restrict__ q, __half* __restrict__ Sp) {
    __shared__ int4v sA[2048];   // 32 KB: 4 a-groups, full K, lo/hi planes

    const int tid  = threadIdx.x;
    const int lane = tid & 63;
    const int w    = tid >> 6;

    const int ablk = blockIdx.x >> 5;
    const int bblk = blockIdx.x & 31;
    const int ag0  = ablk * 4;
    const int bg0  = bblk * 8 + w * 2;

    // stage A: 2048 units; LDS chunk = ai*8 + ks*2 + h (64 units each).
#pragma unroll
    for (int i = 0; i < 8; i++) {
        const int chunk = i * 4 + w;              // wave-uniform
        const int ai = chunk >> 3;
        const int ks = (chunk >> 1) & 3;
        const int h  = chunk & 1;
        const int4v* g = q + h * 65536 + ((ag0 + ai) * 4 + ks) * 64 + lane;
        int4v* l = &sA[chunk * 64];
        __builtin_amdgcn_global_load_lds((gptr_as1)g, (lptr_as3)l, 16, 0, 0);
    }
    __syncthreads();

    const int4v* zq = q + 131072;

    float16 acc[4][2];
#pragma unroll
    for (int ai = 0; ai < 4; ai++)
#pragma unroll
        for (int bi = 0; bi < 2; bi++)
#pragma unroll
            for (int r = 0; r < 16; r++) acc[ai][bi][r] = 0.0f;

#pragma unroll
    for (int ks = 0; ks < 4; ks++) {
        const int u0 = ((bg0 + 0) * 4 + ks) * 64 + lane;
        const int u1 = ((bg0 + 1) * 4 + ks) * 64 + lane;
        int8v Ba = mk8(zq[u0], zq[65536 + u0]);
        int8v Bb = mk8(zq[u1], zq[65536 + u1]);
#pragma unroll
        for (int ai = 0; ai < 4; ai++) {
            const int base = (ai * 8 + ks * 2) * 64 + lane;
            int8v Af = mk8(sA[base], sA[base + 64]);
            acc[ai][0] = MFMA_FP8(Af, Ba, acc[ai][0]);
            acc[ai][1] = MFMA_FP8(Af, Bb, acc[ai][1]);
        }
    }

#pragma unroll
    for (int ai = 0; ai < 4; ai++)
#pragma unroll
        for (int bi = 0; bi < 2; bi++)
            tile_epilogue_sp(acc[ai][bi], Sp, ag0 + ai, bg0 + bi, lane);
}

// ======================= bf16 fallback (R10-proven) =======================
__global__ void conv_kernel(const float* __restrict__ x,
                            const float* __restrict__ z,
                            short8* __restrict__ outbf,
                            float* __restrict__ out0) {
    const int uid = blockIdx.x * 256 + threadIdx.x;
    if (uid == 0) out0[0] = 0.0f;
    const int u = uid & 262143;
    const float* src = (uid < 262144) ? x : z;
    const int g  = u >> 10;
    const int r  = u & 1023;
    const int ks = r >> 6;
    const int h  = (r >> 5) & 1;
    const int l  = r & 31;
    outbf[uid] = cvt8(src + ((g * 32 + l) * KDIM + ks * 16 + h * 8));
}

__device__ __forceinline__ void tile_epilogue_bf(const float16& c, float* __restrict__ S,
                                                 int a, int b, int lane) {
    float m8[8], m4[4];
#pragma unroll
    for (int r = 0; r < 8; r++) m8[r] = fmaxf(c[2 * r], c[2 * r + 1]);
#pragma unroll
    for (int r = 0; r < 4; r++) m4[r] = fmaxf(m8[2 * r], m8[2 * r + 1]);
    float m = fmaxf(fmaxf(m4[0], m4[1]), fmaxf(m4[2], m4[3]));
    m = fmaxf(m, __shfl_xor(m, 32, 64));

    float s0 = 0.f, s1 = 0.f, s2 = 0.f, s3 = 0.f;
    float w0 = 0.f, w1 = 0.f, w2 = 0.f, w3 = 0.f;
#pragma unroll
    for (int r = 0; r < 16; r += 4) {
        float e0 = __expf(c[r + 0] - m);
        float e1 = __expf(c[r + 1] - m);
        float e2 = __expf(c[r + 2] - m);
        float e3 = __expf(c[r + 3] - m);
        s0 += e0; s1 += e1; s2 += e2; s3 += e3;
        w0 = fmaf(e0, c[r + 0], w0);
        w1 = fmaf(e1, c[r + 1], w1);
        w2 = fmaf(e2, c[r + 2], w2);
        w3 = fmaf(e3, c[r + 3], w3);
    }
    float se  = (s0 + s1) + (s2 + s3);
    float swe = (w0 + w1) + (w2 + w3);
    se  += __shfl_xor(se, 32, 64);
    swe += __shfl_xor(swe, 32, 64);
    float cv = swe * __builtin_amdgcn_rcpf(se);
#pragma unroll
    for (int off = 1; off < 32; off <<= 1) cv += __shfl_xor(cv, off, 64);
    if (lane == 0) S[a * NTOK + b] = cv * (1.0f / 32.0f);
}

#define MFMA_BF16 __builtin_amdgcn_mfma_f32_32x32x16_bf16

template <bool F32SRC>
__global__ __launch_bounds__(256, 2)
void sim_kernel(const short8* __restrict__ xbf, const short8* __restrict__ zbf,
                const float* __restrict__ xf, const float* __restrict__ zf,
                float* __restrict__ S) {
    __shared__ short8 sA[4096];

    const int tid  = threadIdx.x;
    const int lane = tid & 63;
    const int w    = tid >> 6;
    const int l31  = lane & 31;
    const int half = lane >> 5;

    const int ablk = blockIdx.x >> 5;
    const int bblk = blockIdx.x & 31;
    const int ag0  = ablk * 4;
    const int bg0  = bblk * 8 + w * 2;

    float16 acc[4][2];
#pragma unroll
    for (int ai = 0; ai < 4; ai++)
#pragma unroll
        for (int bi = 0; bi < 2; bi++)
#pragma unroll
            for (int r = 0; r < 16; r++) acc[ai][bi][r] = 0.0f;

    if (!F32SRC) {
        const short8* asrc = xbf + (size_t)ablk * 4096;
#pragma unroll
        for (int i = 0; i < 16; i++) {
            const short8* g = asrc + i * 256 + w * 64 + lane;
            short8* l = &sA[i * 256 + w * 64];
            __builtin_amdgcn_global_load_lds((gptr_as1)g, (lptr_as3)l, 16, 0, 0);
        }
        __syncthreads();

        const short8* pb0 = zbf + (bg0 + 0) * 1024 + lane;
        const short8* pb1 = zbf + (bg0 + 1) * 1024 + lane;
        short8 Ba = pb0[0];
        short8 Bb = pb1[0];
#pragma unroll
        for (int ks = 0; ks < 16; ks++) {
            short8 Na, Nb;
            if (ks < 15) { Na = pb0[(ks + 1) * 64]; Nb = pb1[(ks + 1) * 64]; }
            short8 A0 = sA[ks * 64 + lane];
            short8 A1 = sA[1024 + ks * 64 + lane];
            short8 A2 = sA[2048 + ks * 64 + lane];
            short8 A3 = sA[3072 + ks * 64 + lane];
            acc[0][0] = MFMA_BF16(A0, Ba, acc[0][0], 0, 0, 0);
            acc[0][1] = MFMA_BF16(A0, Bb, acc[0][1], 0, 0, 0);
            acc[1][0] = MFMA_BF16(A1, Ba, acc[1][0], 0, 0, 0);
            acc[1][1] = MFMA_BF16(A1, Bb, acc[1][1], 0, 0, 0);
            acc[2][0] = MFMA_BF16(A2, Ba, acc[2][0], 0, 0, 0);
            acc[2][1] = MFMA_BF16(A2, Bb, acc[2][1], 0, 0, 0);
            acc[3][0] = MFMA_BF16(A3, Ba, acc[3][0], 0, 0, 0);
            acc[3][1] = MFMA_BF16(A3, Bb, acc[3][1], 0, 0, 0);
            Ba = Na; Bb = Nb;
        }
    } else {
        const float* fb0 = zf + (((bg0 + 0) * 32 + l31) * KDIM + half * 8);
        const float* fb1 = zf + (((bg0 + 1) * 32 + l31) * KDIM + half * 8);
#pragma unroll 1
        for (int ks = 0; ks < 16; ks++) {
            short8 Ba = cvt8(fb0 + ks * 16);
            short8 Bb = cvt8(fb1 + ks * 16);
#pragma unroll
            for (int ai = 0; ai < 4; ai++) {
                const float* fa = xf + (((ag0 + ai) * 32 + l31) * KDIM + half * 8);
                short8 Af = cvt8(fa + ks * 16);
                acc[ai][0] = MFMA_BF16(Af, Ba, acc[ai][0], 0, 0, 0);
                acc[ai][1] = MFMA_BF16(Af, Bb, acc[ai][1], 0, 0, 0);
            }
        }
    }

#pragma unroll
    for (int ai = 0; ai < 4; ai++)
#pragma unroll
        for (int bi = 0; bi < 2; bi++)
            tile_epilogue_bf(acc[ai][bi], S, ag0 + ai, bg0 + bi, lane);
}

// ======================= reductions =======================
__global__ void red_kernel(const __half* __restrict__ Sp, float* __restrict__ S) {
    const int t = blockIdx.x * 256 + threadIdx.x;
    const __half2* h2 = (const __half2*)(Sp + (size_t)t * 64);
    float s = 0.0f;
#pragma unroll
    for (int i = 0; i < 32; i++) {
        float2 f = __half22float2(h2[i]);
        s += f.x + f.y;
    }
    S[t] = s * (1.0f / 64.0f);
}

__global__ void loss_part(const float* __restrict__ S, float* __restrict__ out) {
    const int lane = threadIdx.x & 63;
    const int wid  = threadIdx.x >> 6;
    const int n    = blockIdx.x * 4 + wid;

    float cv[4], rv[4];
#pragma unroll
    for (int k = 0; k < 4; k++) {
        const int t = lane + 64 * k;
        cv[k] = S[t * NTOK + n];
        rv[k] = S[n * NTOK + t];
    }
    float m = fmaxf(fmaxf(cv[0], cv[1]), fmaxf(cv[2], cv[3]));
#pragma unroll
    for (int off = 1; off < 64; off <<= 1) m = fmaxf(m, __shfl_xor(m, off, 64));
    float s = 0.0f;
#pragma unroll
    for (int k = 0; k < 4; k++) s += __expf(cv[k] - m);
#pragma unroll
    for (int off = 1; off < 64; off <<= 1) s += __shfl_xor(s, off, 64);
    float lse_col = m + __logf(s);

    float m2 = fmaxf(fmaxf(rv[0], rv[1]), fmaxf(rv[2], rv[3]));
#pragma unroll
    for (int off = 1; off < 64; off <<= 1) m2 = fmaxf(m2, __shfl_xor(m2, off, 64));
    float s2 = 0.0f;
#pragma unroll
    for (int k = 0; k < 4; k++) s2 += __expf(rv[k] - m2);
#pragma unroll
    for (int off = 1; off < 64; off <<= 1) s2 += __shfl_xor(s2, off, 64);
    float lse_row = m2 + __logf(s2);

    __shared__ float red[4];
    if (lane == 0) {
        float diag = S[n * NTOK + n];
        red[wid] = (lse_col - diag) + (lse_row - diag);
    }
    __syncthreads();
    if (threadIdx.x == 0)
        atomicAdd(out, (red[0] + red[1] + red[2] + red[3]) * (1.0f / 256.0f));
}

__global__ void zero_kernel(float* __restrict__ out) {
    out[0] = 0.0f;
}

extern "C" void kernel_launch(void* const* d_in, const int* in_sizes, int n_in,
                              void* d_out, int out_size, void* d_ws, size_t ws_size,
                              hipStream_t stream) {
    const float* x = (const float*)d_in[0];   // [256,32,256]
    const float* z = (const float*)d_in[1];   // [256,32,256]
    float* out = (float*)d_out;

    const size_t q_bytes  = 262144ull * 16ull;           // 4 MB fp8 (lo/hi planes)
    const size_t sp_bytes = 65536ull * 64ull * 2ull;     // 8 MB fp16 Sp
    const size_t s_bytes  = 256ull * 256ull * 4ull;      // 256 KB
    const size_t bf_bytes = 524288ull * 16ull;           // 8 MB bf16 (fallback)

    if (ws_size >= q_bytes + sp_bytes + s_bytes) {
        int4v*  q  = (int4v*)d_ws;
        __half* Sp = (__half*)((char*)d_ws + q_bytes);
        float*  S  = (float*)((char*)d_ws + q_bytes + sp_bytes);
        conv_fp8<<<512, 256, 0, stream>>>(x, z, q, out);
        sim_fp8<<<2048, 256, 0, stream>>>(q, Sp);
        red_kernel<<<256, 256, 0, stream>>>(Sp, S);
        loss_part<<<64, 256, 0, stream>>>(S, out);
    } else if (ws_size >= bf_bytes + s_bytes) {
        short8* xbf = (short8*)d_ws;
        short8* zbf = xbf + 262144;
        float*  S   = (float*)((char*)d_ws + bf_bytes);
        conv_kernel<<<2048, 256, 0, stream>>>(x, z, (short8*)d_ws, out);
        sim_kernel<false><<<2048, 256, 0, stream>>>(xbf, zbf, nullptr, nullptr, S);
        loss_part<<<64, 256, 0, stream>>>(S, out);
    } else {
        float* S = (float*)d_ws;
        zero_kernel<<<1, 1, 0, stream>>>(out);
        sim_kernel<true><<<2048, 256, 0, stream>>>(nullptr, nullptr, x, z, S);
        loss_part<<<64, 256, 0, stream>>>(S, out);
    }
}